// Round 1
// baseline (48.963 us; speedup 1.0000x reference)
//
#include <hip/hip_runtime.h>

// Single-level 1D inverse DWT, cyclic boundary, 4-tap synthesis filters.
// x: [32, 64, 16384, 1] f32 -> rows of M=16384; last = row[0:8192], detail = row[8192:16384].
// Derivation: out[n] = sum_j lp_rev[j]*U_low[(n+j-zh) mod M] + sum_j hp_rev[j]*U_det[(n+j-zl) mod M]
// with U_low[k]=last[k/2] (k even), U_det[k]=det[(k-1)/2] (k odd). For each output parity exactly
// 2 taps of each filter survive; offsets collapse to d in [-2,1] on the half-length arrays.

#define NPRIME 8192
#define FULLM  (2 * NPRIME)

__device__ __forceinline__ float pick4(float a, float b, float c, float d, int off) {
    // returns window element at (off + 2): off=-2 -> a, -1 -> b, 0 -> c, 1 -> d
    float r = (off <= -2) ? a : b;
    r = (off == 0) ? c : r;
    r = (off >= 1) ? d : r;
    return r;
}

__global__ __launch_bounds__(256) void idwt1d_kernel(
    const float* __restrict__ x,
    const float* __restrict__ lp,
    const float* __restrict__ hp,
    const int* __restrict__ zlp_p,
    const int* __restrict__ zhp_p,
    float* __restrict__ out,
    int nrows)
{
    const int tid = blockIdx.x * blockDim.x + threadIdx.x;
    const int thrPerRow = NPRIME / 4;           // each thread: 4 pairs = 8 outputs
    const int row = tid / thrPerRow;
    if (row >= nrows) return;
    const int p0 = (tid - row * thrPerRow) * 4;

    const int zh = *zhp_p;   // NOTE: per reference, lp path pads with zero_hp
    const int zl = *zlp_p;   //       and hp path pads with zero_lp

    // lp (low) path, zero = zh. Surviving taps land on even upsample indices.
    const int j0e = zh & 1;                  // tap parity for even outputs
    const int d0  = (j0e - zh) / 2;          // even diff -> exact division
    const int j0o = 1 - j0e;                 // tap parity for odd outputs
    const int d1  = (1 + j0o - zh) / 2;
    const float A0 = lp[3 - j0e], A1 = lp[1 - j0e];
    const float A2 = lp[3 - j0o], A3 = lp[1 - j0o];

    // hp (detail) path, zero = zl. Surviving taps land on odd upsample indices.
    const int j1e = (zl + 1) & 1;
    const int e0  = (j1e - zl - 1) / 2;
    const int j1o = zl & 1;
    const int e1  = (j1o - zl) / 2;
    const float B0 = hp[3 - j1e], B1 = hp[1 - j1e];
    const float B2 = hp[3 - j1o], B3 = hp[1 - j1o];

    const size_t rb = (size_t)row * FULLM;
    const float* lastp = x + rb;
    const float* detp  = lastp + NPRIME;

    // register windows w[i] = arr[(p0 - 2 + i) mod N'], i in 0..7
    const int im2 = (p0 == 0) ? (NPRIME - 2) : (p0 - 2);
    const int im1 = (p0 == 0) ? (NPRIME - 1) : (p0 - 1);
    const int i4  = (p0 + 4 == NPRIME) ? 0 : (p0 + 4);
    const int i5  = (p0 + 4 == NPRIME) ? 1 : (p0 + 5);

    float wl[8], wd[8];
    {
        const float4 v = *reinterpret_cast<const float4*>(lastp + p0);
        wl[0] = lastp[im2]; wl[1] = lastp[im1];
        wl[2] = v.x; wl[3] = v.y; wl[4] = v.z; wl[5] = v.w;
        wl[6] = lastp[i4];  wl[7] = lastp[i5];
        const float4 u = *reinterpret_cast<const float4*>(detp + p0);
        wd[0] = detp[im2];  wd[1] = detp[im1];
        wd[2] = u.x; wd[3] = u.y; wd[4] = u.z; wd[5] = u.w;
        wd[6] = detp[i4];   wd[7] = detp[i5];
    }

    // shift windows by the (wave-uniform) runtime offsets via cndmask selects —
    // keeps everything in registers (no runtime-indexed local arrays -> no scratch)
    float sle[5], slo[5], sde[5], sdo[5];
    #pragma unroll
    for (int i = 0; i < 5; ++i) {
        sle[i] = pick4(wl[i], wl[i+1], wl[i+2], wl[i+3], d0);
        slo[i] = pick4(wl[i], wl[i+1], wl[i+2], wl[i+3], d1);
        sde[i] = pick4(wd[i], wd[i+1], wd[i+2], wd[i+3], e0);
        sdo[i] = pick4(wd[i], wd[i+1], wd[i+2], wd[i+3], e1);
    }

    float r[8];
    #pragma unroll
    for (int k = 0; k < 4; ++k) {
        r[2*k]   = A0 * sle[k] + A1 * sle[k+1] + B0 * sde[k] + B1 * sde[k+1];
        r[2*k+1] = A2 * slo[k] + A3 * slo[k+1] + B2 * sdo[k] + B3 * sdo[k+1];
    }

    float* op = out + rb + 2 * (size_t)p0;
    reinterpret_cast<float4*>(op)[0] = make_float4(r[0], r[1], r[2], r[3]);
    reinterpret_cast<float4*>(op)[1] = make_float4(r[4], r[5], r[6], r[7]);
}

extern "C" void kernel_launch(void* const* d_in, const int* in_sizes, int n_in,
                              void* d_out, int out_size, void* d_ws, size_t ws_size,
                              hipStream_t stream) {
    const float* x  = (const float*)d_in[0];
    const float* lp = (const float*)d_in[1];
    const float* hp = (const float*)d_in[2];
    const int* zlp  = (const int*)d_in[3];
    const int* zhp  = (const int*)d_in[4];
    float* out = (float*)d_out;

    const int nrows = in_sizes[0] / FULLM;            // 32*64 = 2048
    const long long total = (long long)nrows * (NPRIME / 4);
    const int block = 256;
    const int grid = (int)((total + block - 1) / block);

    idwt1d_kernel<<<grid, block, 0, stream>>>(x, lp, hp, zlp, zhp, out, nrows);
}

// Round 2
// 46.161 us; speedup vs baseline: 1.0607x; 1.0607x over previous
//
#include <hip/hip_runtime.h>

// Single-level 1D inverse DWT, cyclic boundary, 4-tap synthesis filters.
// x: [32, 64, 16384, 1] f32 -> rows of M=16384; last = row[0:8192], detail = row[8192:16384].
// out[2p]   and out[2p+1] are each 2 lp-taps on 'last' + 2 hp-taps on 'det' with
// offsets d in [-2,1] derived from the zero_* scalars (see R0 derivation).
//
// R1 change: halo elements come from neighbor lanes via shfl (wave=64) instead of
// 8 scalar global loads/thread -> vmem instrs per thread 12 -> ~4 (issue-bound fix).
// Rows are 2048 threads (wave-aligned), so the cyclic wrap only occurs at lane 0
// of the row's first wave / lane 63 of its last wave; those lanes (and only those)
// take exec-masked scalar loads.

#define NPRIME 8192
#define FULLM  (2 * NPRIME)

__device__ __forceinline__ float pick4(float a, float b, float c, float d, int off) {
    // window element at (off + 2): off=-2 -> a, -1 -> b, 0 -> c, 1 -> d
    float r = (off <= -2) ? a : b;
    r = (off == 0) ? c : r;
    r = (off >= 1) ? d : r;
    return r;
}

__global__ __launch_bounds__(256) void idwt1d_kernel(
    const float* __restrict__ x,
    const float* __restrict__ lp,
    const float* __restrict__ hp,
    const int* __restrict__ zlp_p,
    const int* __restrict__ zhp_p,
    float* __restrict__ out,
    int nrows)
{
    const int tid = blockIdx.x * blockDim.x + threadIdx.x;
    const int thrPerRow = NPRIME / 4;           // each thread: 4 pairs = 8 outputs
    const int row = tid / thrPerRow;
    if (row >= nrows) return;
    const int p0 = (tid - row * thrPerRow) * 4;
    const int lane = threadIdx.x & 63;

    const int zh = *zhp_p;   // NOTE: per reference, lp path pads with zero_hp
    const int zl = *zlp_p;   //       and hp path pads with zero_lp

    // lp (low) path, zero = zh. Surviving taps land on even upsample indices.
    const int j0e = zh & 1;
    const int d0  = (j0e - zh) / 2;
    const int j0o = 1 - j0e;
    const int d1  = (1 + j0o - zh) / 2;
    const float A0 = lp[3 - j0e], A1 = lp[1 - j0e];
    const float A2 = lp[3 - j0o], A3 = lp[1 - j0o];

    // hp (detail) path, zero = zl. Surviving taps land on odd upsample indices.
    const int j1e = (zl + 1) & 1;
    const int e0  = (j1e - zl - 1) / 2;
    const int j1o = zl & 1;
    const int e1  = (j1o - zl) / 2;
    const float B0 = hp[3 - j1e], B1 = hp[1 - j1e];
    const float B2 = hp[3 - j1o], B3 = hp[1 - j1o];

    const size_t rb = (size_t)row * FULLM;
    const float* lastp = x + rb;
    const float* detp  = lastp + NPRIME;

    const float4 v = *reinterpret_cast<const float4*>(lastp + p0);
    const float4 u = *reinterpret_cast<const float4*>(detp + p0);

    // halo via wave shuffles: lane-1 holds [p0-4..p0-1], lane+1 holds [p0+4..p0+7]
    float wl0 = __shfl_up(v.z, 1), wl1 = __shfl_up(v.w, 1);
    float wl6 = __shfl_down(v.x, 1), wl7 = __shfl_down(v.y, 1);
    float wd0 = __shfl_up(u.z, 1), wd1 = __shfl_up(u.w, 1);
    float wd6 = __shfl_down(u.x, 1), wd7 = __shfl_down(u.y, 1);

    if (lane == 0) {   // previous wave's data (or cyclic wrap at p0==0)
        const int im2 = (p0 == 0) ? (NPRIME - 2) : (p0 - 2);
        const int im1 = (p0 == 0) ? (NPRIME - 1) : (p0 - 1);
        wl0 = lastp[im2]; wl1 = lastp[im1];
        wd0 = detp[im2];  wd1 = detp[im1];
    }
    if (lane == 63) {  // next wave's data (or cyclic wrap at p0+4==NPRIME)
        const int i4 = (p0 + 4 == NPRIME) ? 0 : (p0 + 4);
        const int i5 = (p0 + 4 == NPRIME) ? 1 : (p0 + 5);
        wl6 = lastp[i4]; wl7 = lastp[i5];
        wd6 = detp[i4];  wd7 = detp[i5];
    }

    const float wl[8] = { wl0, wl1, v.x, v.y, v.z, v.w, wl6, wl7 };
    const float wd[8] = { wd0, wd1, u.x, u.y, u.z, u.w, wd6, wd7 };

    // shift windows by the (wave-uniform) runtime offsets via cndmask selects
    float sle[5], slo[5], sde[5], sdo[5];
    #pragma unroll
    for (int i = 0; i < 5; ++i) {
        sle[i] = pick4(wl[i], wl[i+1], wl[i+2], wl[i+3], d0);
        slo[i] = pick4(wl[i], wl[i+1], wl[i+2], wl[i+3], d1);
        sde[i] = pick4(wd[i], wd[i+1], wd[i+2], wd[i+3], e0);
        sdo[i] = pick4(wd[i], wd[i+1], wd[i+2], wd[i+3], e1);
    }

    float r[8];
    #pragma unroll
    for (int k = 0; k < 4; ++k) {
        r[2*k]   = A0 * sle[k] + A1 * sle[k+1] + B0 * sde[k] + B1 * sde[k+1];
        r[2*k+1] = A2 * slo[k] + A3 * slo[k+1] + B2 * sdo[k] + B3 * sdo[k+1];
    }

    float* op = out + rb + 2 * (size_t)p0;
    reinterpret_cast<float4*>(op)[0] = make_float4(r[0], r[1], r[2], r[3]);
    reinterpret_cast<float4*>(op)[1] = make_float4(r[4], r[5], r[6], r[7]);
}

extern "C" void kernel_launch(void* const* d_in, const int* in_sizes, int n_in,
                              void* d_out, int out_size, void* d_ws, size_t ws_size,
                              hipStream_t stream) {
    const float* x  = (const float*)d_in[0];
    const float* lp = (const float*)d_in[1];
    const float* hp = (const float*)d_in[2];
    const int* zlp  = (const int*)d_in[3];
    const int* zhp  = (const int*)d_in[4];
    float* out = (float*)d_out;

    const int nrows = in_sizes[0] / FULLM;            // 32*64 = 2048
    const long long total = (long long)nrows * (NPRIME / 4);
    const int block = 256;
    const int grid = (int)((total + block - 1) / block);

    idwt1d_kernel<<<grid, block, 0, stream>>>(x, lp, hp, zlp, zhp, out, nrows);
}